// Round 7
// baseline (10904.292 us; speedup 1.0000x reference)
//
#include <hip/hip_runtime.h>
#include <hip/hip_fp16.h>
#include <stdint.h>

typedef uint32_t u32;
typedef uint64_t u64;
typedef unsigned int v4u __attribute__((ext_vector_type(4)));
typedef float v4f __attribute__((ext_vector_type(4)));
typedef _Float16 v2h __attribute__((ext_vector_type(2)));

constexpr int CB   = 8192;   // batch
constexpr int CG   = 689;    // genes
constexpr int CL   = 6;      // scanned layers
constexpr int CS   = 2785;   // layer width
constexpr int CSP  = 2816;   // padded width for tables
constexpr int CRS  = 8256;   // row stride (elements); 16512 B, 16B-aligned, not 4KB-periodic
constexpr int KCAP = 112;    // max nnz per column (mean 55.7, sd 7.4 -> +7.6 sigma), mult of 8
constexpr int TILE = 32;     // columns per build block
constexpr int NTIL = 88;     // CSP / TILE (covers all padded columns)
constexpr int RSPL = 8;      // row-splits per (table, tile)
constexpr int LCAP = 40;     // per-slice per-column bucket cap (mean ~7, +12.6 sigma)

constexpr int NB   = 2048;   // persistent blocks: EXACTLY 8/CU x 256 CU (co-resident)
constexpr int NTH  = 256;    // 4 waves/block
constexpr int NWPX = 1024;   // waves per XCD (NB/8 * 4)

union V16 { v4u u; v2h h2[4]; };
union F4  { v4f v; float f[4]; u32 u[4]; };
union HW  { u32 u; v2h h; };

// ---- build CSC tables, all 7 tables in one kernel ----
// Entry u32 {row:16 | half(w):16}. (tbl, row-slice, 32-col tile) per block;
// LDS bucket + one global atomicAdd per column + compact coalesced write-out.
__global__ __launch_bounds__(256) void build_tables(const float* __restrict__ lm0,
                                                    const float* __restrict__ W0,
                                                    const float* __restrict__ lm,
                                                    const float* __restrict__ W,
                                                    u32* __restrict__ ent,
                                                    int* __restrict__ cnt)
{
    __shared__ u32 eL[TILE * LCAP];   // 5,120 B
    __shared__ int cL[TILE];
    __shared__ int bL[TILE];

    int tbl   = blockIdx.z;                      // 0 = depth-0, 1..6 = scanned
    int slice = blockIdx.y;                      // row slice 0..RSPL-1
    int x     = blockIdx.x;                      // 0..87
    int tile  = (x & 7) * (NTIL / 8) + (x >> 3); // XCD k -> tiles [11k, 11k+11)
    int s0    = tile * TILE;

    const float* mbase; const float* wbase; int nrows;
    if (tbl == 0) { mbase = lm0; wbase = W0; nrows = CG; }
    else {
        size_t off = (size_t)(tbl - 1) * CS * CS;
        mbase = lm + off; wbase = W + off; nrows = CS;
    }
    int r0 = slice * nrows / RSPL;
    int r1 = (slice + 1) * nrows / RSPL;

    int t = threadIdx.x;
    if (t < TILE) cL[t] = 0;
    __syncthreads();

    int rl = t >> 3;             // row-in-pass 0..31
    int cq = (t & 7) * 4;        // col-quad base within tile
    int c  = s0 + cq;            // global col of quad

    for (int p = r0; p < r1; p += 32) {
        int r = p + rl;
        if (r >= r1) continue;
        const float* mr = mbase + (size_t)r * CS;
        if (c + 3 < CS) {
            F4 m4; m4.v = *reinterpret_cast<const v4f*>(mr + c);
            if ((m4.u[0] | m4.u[1] | m4.u[2] | m4.u[3]) == 0u) continue;
            F4 w4; w4.v = *reinterpret_cast<const v4f*>(wbase + (size_t)r * CS + c);
            u32 hi = (u32)r << 16;
#pragma unroll
            for (int q = 0; q < 4; q++) {
                if (m4.f[q] != 0.0f) {
                    int pos = atomicAdd(&cL[cq + q], 1);
                    if (pos < LCAP) {
                        u32 hw = (u32)__half_as_ushort(__float2half(w4.f[q]));
                        eL[(cq + q) * LCAP + pos] = hi | hw;
                    }
                }
            }
        } else {
            u32 hi = (u32)r << 16;
            for (int q = 0; q < 4; q++) {
                int cc = c + q;
                if (cc >= CS) break;
                float m = mr[cc];
                if (m != 0.0f) {
                    int pos = atomicAdd(&cL[cq + q], 1);
                    if (pos < LCAP) {
                        u32 hw = (u32)__half_as_ushort(__float2half(wbase[(size_t)r * CS + cc]));
                        eL[(cq + q) * LCAP + pos] = hi | hw;
                    }
                }
            }
        }
    }
    __syncthreads();

    // reserve global segments (1 atomic per column) and write compactly
    int col = t >> 3, sub = t & 7;
    int gc  = tbl * CSP + s0 + col;
    int n = cL[col]; if (n > LCAP) n = LCAP;
    if (sub == 0) bL[col] = atomicAdd(&cnt[gc], n);
    __syncthreads();
    int base = bL[col];
    u32* eg = ent + (size_t)gc * KCAP;
    for (int i = sub; i < n; i += 8) {
        int pos = base + i;
        if (pos < KCAP) eg[pos] = eL[col * LCAP + i];
    }
}

// ---- device-wide barrier (generation counter; all NB blocks co-resident) ----
__device__ __forceinline__ void gridbar(int* bar)
{
    __syncthreads();                 // drains this block's vmem (compiler emits vmcnt(0))
    if (threadIdx.x == 0) {
        __threadfence();             // make this XCD's writes device-visible
        int* cnt = bar;
        int* gen = bar + 4;          // separate cacheline-ish
        int g = __hip_atomic_load(gen, __ATOMIC_ACQUIRE, __HIP_MEMORY_SCOPE_AGENT);
        int old = __hip_atomic_fetch_add(cnt, 1, __ATOMIC_ACQ_REL, __HIP_MEMORY_SCOPE_AGENT);
        if (old == NB - 1) {
            __hip_atomic_store(cnt, 0, __ATOMIC_RELAXED, __HIP_MEMORY_SCOPE_AGENT);
            __hip_atomic_fetch_add(gen, 1, __ATOMIC_ACQ_REL, __HIP_MEMORY_SCOPE_AGENT);
        } else {
            while (__hip_atomic_load(gen, __ATOMIC_ACQUIRE, __HIP_MEMORY_SCOPE_AGENT) == g)
                __builtin_amdgcn_s_sleep(8);
        }
        __threadfence();             // invalidate stale lines before next phase reads
    }
    __syncthreads();
}

// ---- gather one (column, batch-chunk) with one wave (r5 proven body) ----
__device__ __forceinline__ void gather_wave(const __half* __restrict__ src,
                                            __half* __restrict__ dst,
                                            const u32* __restrict__ ent,
                                            const int* __restrict__ cnt,
                                            const float* __restrict__ bias,
                                            float* __restrict__ sumv,
                                            float* __restrict__ sumq,
                                            int s, int boff, int lane)
{
    int n = cnt[s]; if (n > KCAP) n = KCAP;
    int ng = (n + 7) >> 3;                  // groups of 8 (pad entries are zeros)
    const u32* e = ent + (size_t)s * KCAP;
    const char* sb = (const char*)src + (size_t)boff * 2;

    float bv = bias[s];
    float acc[8];
#pragma unroll
    for (int j = 0; j < 8; j++) acc[j] = bv;

    for (int g = 0; g < ng; g++) {
        u32 ev[8];
#pragma unroll
        for (int q = 0; q < 8; q++) ev[q] = e[g * 8 + q];
        V16 rv[8];
#pragma unroll
        for (int q = 0; q < 8; q++)
            rv[q].u = *reinterpret_cast<const v4u*>(sb + (size_t)(ev[q] >> 16) * (CRS * 2));
#if __has_builtin(__builtin_amdgcn_fdot2) && __has_builtin(__builtin_amdgcn_perm)
#pragma unroll
        for (int pq = 0; pq < 4; pq++) {
            u32 e0 = ev[2 * pq], e1 = ev[2 * pq + 1];
            HW w2; w2.u = (e0 & 0xffffu) | (e1 << 16);   // {w_q, w_q1}
#pragma unroll
            for (int j = 0; j < 4; j++) {
                u32 a = rv[2 * pq].u[j], b = rv[2 * pq + 1].u[j];
                HW lo; lo.u = __builtin_amdgcn_perm(b, a, 0x05040100u);
                HW hi; hi.u = __builtin_amdgcn_perm(b, a, 0x07060302u);
                acc[2*j]   = __builtin_amdgcn_fdot2(lo.h, w2.h, acc[2*j],   false);
                acc[2*j+1] = __builtin_amdgcn_fdot2(hi.h, w2.h, acc[2*j+1], false);
            }
        }
#else
#pragma unroll
        for (int q = 0; q < 8; q++) {
            HW w2; w2.u = ev[q] & 0xffffu;
#pragma unroll
            for (int j = 0; j < 4; j++) {
                float2 f = __half22float2(*(const __half2*)&rv[q].h2[j]);
                float w = __half2float(*(const __half*)&w2.h);
                acc[2*j]   = fmaf(w, f.x, acc[2*j]);
                acc[2*j+1] = fmaf(w, f.y, acc[2*j+1]);
            }
        }
#endif
    }

    V16 o;
#pragma unroll
    for (int j = 0; j < 4; j++) {
        v2h p; p.x = (_Float16)acc[2*j]; p.y = (_Float16)acc[2*j+1];
        o.h2[j] = p;
    }
    __builtin_nontemporal_store(o.u, reinterpret_cast<v4u*>(dst + (size_t)s * CRS + boff));

    float ls = 0.f, lq = 0.f;
#pragma unroll
    for (int j = 0; j < 8; j++) { ls += acc[j]; lq += acc[j] * acc[j]; }
#pragma unroll
    for (int off = 32; off > 0; off >>= 1) {
        ls += __shfl_xor(ls, off);
        lq += __shfl_xor(lq, off);
    }
    if (lane == 0) { atomicAdd(&sumv[s], ls); atomicAdd(&sumq[s], lq); }
}

// ---- BN+tanh+skip for one (column, batch-chunk) with one wave ----
__device__ __forceinline__ void bn_wave(__half* __restrict__ h,
                                        const __half* __restrict__ prev,
                                        const float* __restrict__ sumv,
                                        const float* __restrict__ sumq,
                                        const float* __restrict__ gamma,
                                        const float* __restrict__ beta,
                                        const float* __restrict__ dlv,
                                        int s, int boff)
{
    float mean = sumv[s] * (1.0f / CB);
    float var  = sumq[s] * (1.0f / CB) - mean * mean;
    float rstd = rsqrtf(var + 1e-5f);
    float scale = gamma[s] * rstd;
    float shift = beta[s] - mean * scale;
    size_t base = (size_t)s * CRS + boff;
    V16 v; v.u = *reinterpret_cast<const v4u*>(h + base);
    V16 pv;
    float d = 0.f;
    if (prev) { d = dlv[s]; pv.u = *reinterpret_cast<const v4u*>(prev + base); }
    V16 o;
#pragma unroll
    for (int j = 0; j < 4; j++) {
        float2 f = __half22float2(*(const __half2*)&v.h2[j]);
        float t0 = tanhf(fmaf(f.x, scale, shift));
        float t1 = tanhf(fmaf(f.y, scale, shift));
        if (prev) {
            float2 p = __half22float2(*(const __half2*)&pv.h2[j]);
            t0 = fmaf(d, p.x, t0);
            t1 = fmaf(d, p.y, t1);
        }
        v2h pk; pk.x = (_Float16)t0; pk.y = (_Float16)t1;
        o.h2[j] = pk;
    }
    *reinterpret_cast<v4u*>(h + base) = o.u;
}

// ---- persistent fused forward pass: transpose+head_prep, 6x(gather,bn),
// gather6, head -- ONE launch, 14 device-wide barriers. NB=2048 blocks x 256
// thr = exactly 8 blocks/CU x 256 CU co-resident; launch_bounds(256,8) pins
// VGPR<=64 so residency is guaranteed (no deadlock). Wave->work mapping keeps
// the XCD/batch-chunk affinity of the old per-kernel grids: block%8 = XCD x
// owns chunks {x, x+8} for BOTH gather and bn -> h stays in XCD-x L2 across
// the bn->gather handoff.
__global__ __launch_bounds__(NTH, 8) void mega(const float* __restrict__ x,
                                               const float* __restrict__ flm,
                                               const float* __restrict__ fasm,
                                               const float* __restrict__ b0,
                                               const float* __restrict__ bb,
                                               const float* __restrict__ gam,
                                               const float* __restrict__ bet,
                                               const float* __restrict__ wout,
                                               const float* __restrict__ bout,
                                               const u32* __restrict__ ent,
                                               const int* __restrict__ cnt,
                                               float* __restrict__ sumv,
                                               float* __restrict__ sumq,
                                               int* __restrict__ hcnt,
                                               int* __restrict__ hs,
                                               float* __restrict__ hc,
                                               __half* __restrict__ hA,
                                               __half* __restrict__ hB,
                                               int* __restrict__ bar,
                                               float* __restrict__ out)
{
    __shared__ float tile[32][33];
    int B    = blockIdx.x;
    int tid  = threadIdx.x;
    int w    = tid >> 6;
    int lane = tid & 63;
    int xcd  = B & 7;
    int widx = (B >> 3) * 4 + w;           // [0, NWPX) per-XCD wave index
    int gw   = B * 4 + w;                  // [0, 8192) global wave

    __half* xT = hB;                       // alias (dead before hB is written)

    // ---- P0: transpose x -> xT (fp16), + head_prep ----
    for (int it = B; it < 5632 + 11; it += NB) {
        if (it < 5632) {
            int bx = it % 22, by = it / 22;
            int gx = bx * 32, gy = by * 32;
            int tx = tid & 31, ty = tid >> 5;
#pragma unroll
            for (int i = 0; i < 32; i += 8) {
                int g = gx + tx, b2 = gy + ty + i;
                tile[ty + i][tx] = (g < CG) ? x[(size_t)b2 * CG + g] : 0.f;
            }
            __syncthreads();
#pragma unroll
            for (int i = 0; i < 32; i += 8) {
                int g = gx + ty + i, b2 = gy + tx;
                if (g < CG) xT[(size_t)g * CRS + b2] = __float2half(tile[tx][ty + i]);
            }
            __syncthreads();
        } else {
            int s = (it - 5632) * 256 + tid;
            if (s < CS) {
                float c = fasm[s] * wout[s];
                if (c != 0.f) {
                    int p = atomicAdd(hcnt, 1);
                    if (p < 64) { hs[p] = s; hc[p] = c; }
                }
            }
        }
    }
    gridbar(bar);

    // ---- 6 layers: gather -> bar -> bn -> bar ----
    const __half* cur = xT;
    __half* bufs[2] = {hA, hB};
    for (int t = 0; t < 6; t++) {
        __half* dst = bufs[t & 1];         // t even -> hA, odd -> hB
        const u32* entp = ent + (size_t)t * CSP * KCAP;
        const int* cntp = cnt + t * CSP;
        const float* biasp = (t == 0) ? b0 : bb + (size_t)(t - 1) * CS;
        float* sv = sumv + t * CSP;
        float* sq = sumq + t * CSP;

        for (int z = 0; z < 2; z++) {
            int boff = z * 4096 + xcd * 512 + lane * 8;
            for (int col = widx; col < CS; col += NWPX)
                gather_wave(cur, dst, entp, cntp, biasp, sv, sq, col, boff, lane);
        }
        gridbar(bar);

        const float* gp = gam + (size_t)t * CS;
        const float* bp = bet + (size_t)t * CS;
        const float* dl = (t == 0) ? nullptr : flm + (size_t)(t - 1) * CS;
        const __half* pv = (t == 0) ? nullptr : cur;
        for (int idx = widx; idx < 2 * CS; idx += NWPX) {
            int half2nd = (idx >= CS);
            int col = half2nd ? idx - CS : idx;
            int boff = (xcd + 8 * half2nd) * 512 + lane * 8;
            bn_wave(dst, pv, sv, sq, gp, bp, dl, col, boff);
        }
        gridbar(bar);
        cur = dst;
    }

    // ---- layer 6: only the head's selected columns (cur == hB, h6 == hA) ----
    __half* h6 = hA;
    if (gw < 1024) {
        int si = gw >> 4, chunk = gw & 15;
        if (si < *hcnt && si < 64) {
            int s = hs[si];
            int boff = (chunk >> 3) * 4096 + (chunk & 7) * 512 + lane * 8;
            gather_wave(cur, h6, ent + (size_t)6 * CSP * KCAP, cnt + 6 * CSP,
                        bb + (size_t)5 * CS, sumv + 6 * CSP, sumq + 6 * CSP,
                        s, boff, lane);
        }
    }
    gridbar(bar);

    // ---- head: fused BN(layer6)+tanh+skip+dot ----
    if (gw < 128) {
        int b = gw * 64 + lane;
        int n = *hcnt; if (n > 64) n = 64;
        float acc = bout[0];
        const float* sv = sumv + 6 * CSP;
        const float* sq = sumq + 6 * CSP;
        const float* gp = gam + (size_t)6 * CS;
        const float* bp = bet + (size_t)6 * CS;
        const float* dl = flm + (size_t)5 * CS;
        for (int k = 0; k < n; k++) {
            int s = hs[k];
            float mean = sv[s] * (1.0f / CB);
            float var  = sq[s] * (1.0f / CB) - mean * mean;
            float rstd = rsqrtf(var + 1e-5f);
            float scale = gp[s] * rstd;
            float shift = bp[s] - mean * scale;
            float pre  = __half2float(h6[(size_t)s * CRS + b]);
            float prev = __half2float(cur[(size_t)s * CRS + b]);
            float hn = tanhf(fmaf(pre, scale, shift)) + dl[s] * prev;
            acc = fmaf(hc[k], hn, acc);
        }
        out[b] = acc;
    }
}

extern "C" void kernel_launch(void* const* d_in, const int* in_sizes, int n_in,
                              void* d_out, int out_size, void* d_ws, size_t ws_size,
                              hipStream_t stream)
{
    const float* x    = (const float*)d_in[0];
    const float* lm0  = (const float*)d_in[1];
    const float* lm   = (const float*)d_in[2];
    const float* flm  = (const float*)d_in[3];
    const float* fasm = (const float*)d_in[4];
    const float* W0   = (const float*)d_in[5];
    const float* b0   = (const float*)d_in[6];
    const float* W    = (const float*)d_in[7];
    const float* bb   = (const float*)d_in[8];
    const float* gam  = (const float*)d_in[9];
    const float* bet  = (const float*)d_in[10];
    const float* wout = (const float*)d_in[11];
    const float* bout = (const float*)d_in[12];
    float* out = (float*)d_out;

    // workspace carve (16B-aligned)
    char* ws = (char*)d_ws;
    int*    cnt  = (int*)ws;                     // 7*2816*4 = 78,848
    float*  sumv = (float*)(ws + 78848);         // 78,848
    float*  sumq = (float*)(ws + 157696);        // 78,848 -> end 236,544
    int*    hcnt = (int*)(ws + 236544);          // 16 B
    int*    hs   = (int*)(ws + 236560);          // 256 B
    float*  hc   = (float*)(ws + 236816);        // 256 B -> end 237,072
    int*    bar  = (int*)(ws + 237088);          // 32 B barrier (zeroed)
    u32*    ent  = (u32*)(ws + 237184);          // 7*2816*112*4 = 8,830,976 -> end 9,068,160
    __half* hA   = (__half*)(ws + 9068160);      // 45,985,920 -> end 55,054,080
    __half* hB   = (__half*)(ws + 55054080);     // 45,985,920 -> end 101,040,000

    // cnt + sums + head scratch + barrier + ent must be zero
    (void)hipMemsetAsync(ws, 0, 9068160, stream);

    build_tables<<<dim3(NTIL, RSPL, 7), 256, 0, stream>>>(lm0, W0, lm, W, ent, cnt);

    mega<<<dim3(NB), dim3(NTH), 0, stream>>>(x, flm, fasm, b0, bb, gam, bet,
        wout, bout, ent, cnt, sumv, sumq, hcnt, hs, hc, hA, hB, bar, out);
}